// Round 1
// baseline (1164.639 us; speedup 1.0000x reference)
//
#include <hip/hip_runtime.h>
#include <math.h>

#define TSEQ 1024
#define NH 16
#define HD 64

// ---------------- fp32 GEMM: C[M,N] = A[M,K] * B[N,K]^T (both row-major) ----
#define BM 128
#define BN 128
#define BK 16

__global__ __launch_bounds__(256) void gemm_nt(
    const float* __restrict__ A, const float* __restrict__ B,
    float* __restrict__ C, int M, int N, int K)
{
  __shared__ float As[BK][BM + 4];
  __shared__ float Bs[BK][BN + 4];
  const int tid = threadIdx.x;
  const int bm = blockIdx.y * BM;
  const int bn = blockIdx.x * BN;
  const int tm = (tid >> 4) << 3;
  const int tn = (tid & 15) << 3;

  float acc[8][8];
#pragma unroll
  for (int i = 0; i < 8; ++i)
#pragma unroll
    for (int j = 0; j < 8; ++j) acc[i][j] = 0.0f;

  const int lr = tid >> 2;          // 0..63
  const int lc = (tid & 3) << 2;    // 0,4,8,12
  const float* Ap = A + (size_t)(bm + lr) * K + lc;
  const float* Bp = B + (size_t)(bn + lr) * K + lc;

  for (int k0 = 0; k0 < K; k0 += BK) {
    float4 a0 = *(const float4*)(Ap + k0);
    float4 a1 = *(const float4*)(Ap + (size_t)64 * K + k0);
    float4 b0 = *(const float4*)(Bp + k0);
    float4 b1 = *(const float4*)(Bp + (size_t)64 * K + k0);
    As[lc + 0][lr] = a0.x; As[lc + 1][lr] = a0.y; As[lc + 2][lr] = a0.z; As[lc + 3][lr] = a0.w;
    As[lc + 0][lr + 64] = a1.x; As[lc + 1][lr + 64] = a1.y; As[lc + 2][lr + 64] = a1.z; As[lc + 3][lr + 64] = a1.w;
    Bs[lc + 0][lr] = b0.x; Bs[lc + 1][lr] = b0.y; Bs[lc + 2][lr] = b0.z; Bs[lc + 3][lr] = b0.w;
    Bs[lc + 0][lr + 64] = b1.x; Bs[lc + 1][lr + 64] = b1.y; Bs[lc + 2][lr + 64] = b1.z; Bs[lc + 3][lr + 64] = b1.w;
    __syncthreads();
#pragma unroll
    for (int kk = 0; kk < BK; ++kk) {
      float4 av0 = *(const float4*)&As[kk][tm];
      float4 av1 = *(const float4*)&As[kk][tm + 4];
      float4 bv0 = *(const float4*)&Bs[kk][tn];
      float4 bv1 = *(const float4*)&Bs[kk][tn + 4];
      float a[8] = {av0.x, av0.y, av0.z, av0.w, av1.x, av1.y, av1.z, av1.w};
      float bb[8] = {bv0.x, bv0.y, bv0.z, bv0.w, bv1.x, bv1.y, bv1.z, bv1.w};
#pragma unroll
      for (int i = 0; i < 8; ++i)
#pragma unroll
        for (int j = 0; j < 8; ++j) acc[i][j] = fmaf(a[i], bb[j], acc[i][j]);
    }
    __syncthreads();
  }
#pragma unroll
  for (int i = 0; i < 8; ++i) {
    float* Cp = C + (size_t)(bm + tm + i) * N + bn + tn;
    *(float4*)Cp = make_float4(acc[i][0], acc[i][1], acc[i][2], acc[i][3]);
    *(float4*)(Cp + 4) = make_float4(acc[i][4], acc[i][5], acc[i][6], acc[i][7]);
  }
}

// ---------------- top-4 |v| sparsify, one wave per 64-vector, in place ------
__global__ __launch_bounds__(256) void sparsify_top4(float* __restrict__ y, int nvec)
{
  const int w = blockIdx.x * 4 + (threadIdx.x >> 6);
  const int lane = threadIdx.x & 63;
  if (w >= nvec) return;
  float* p = y + (size_t)w * 64;
  const float v = p[lane];
  float ak = fabsf(v);      // working key; -1 once consumed
  bool sel = false;
#pragma unroll
  for (int it = 0; it < 4; ++it) {
    float bv = ak; int bl = lane;
#pragma unroll
    for (int off = 32; off > 0; off >>= 1) {
      float ov = __shfl_xor(bv, off);
      int   ol = __shfl_xor(bl, off);
      if (ov > bv || (ov == bv && ol < bl)) { bv = ov; bl = ol; }
    }
    if (lane == bl) { sel = true; ak = -1.0f; }
  }
  p[lane] = sel ? v : 0.0f;
}

// ---------------- K relayout: [b,t,h,j] -> KT [bh, j, t] --------------------
__global__ __launch_bounds__(256) void transpose_k(
    const float* __restrict__ Ky, float* __restrict__ KT)
{
  __shared__ float tile[64][65];
  const int bh = blockIdx.y;
  const int b = bh >> 4, h = bh & 15;
  const int t0 = blockIdx.x * 64;
  const int tid = threadIdx.x;
  {
    const int j = tid & 63, r = tid >> 6;
#pragma unroll
    for (int i = 0; i < 16; ++i) {
      const int tl = r * 16 + i;
      tile[tl][j] = Ky[(size_t)(b * TSEQ + t0 + tl) * 1024 + h * HD + j];
    }
  }
  __syncthreads();
  {
    const int tl = tid & 63, jr = tid >> 6;
#pragma unroll
    for (int i = 0; i < 16; ++i) {
      const int jl = jr * 16 + i;
      KT[((size_t)(bh * HD + jl)) * TSEQ + t0 + tl] = tile[tl][jl];
    }
  }
}

// ---------------- attention: one block per (q, bh) --------------------------
__device__ __forceinline__ unsigned mono_key(float f) {
  unsigned b = __float_as_uint(f);
  return (b & 0x80000000u) ? ~b : (b | 0x80000000u);
}

__global__ __launch_bounds__(256) void attn_sparse(
    const float* __restrict__ Qy, const float* __restrict__ KT,
    const float* __restrict__ Vy, float* __restrict__ Oy)
{
  const int q  = blockIdx.x;
  const int bh = blockIdx.y;
  const int b  = bh >> 4;
  const int h  = bh & 15;
  const int tid  = threadIdx.x;
  const int lane = tid & 63;
  const int wid  = tid >> 6;

  __shared__ float    sc[TSEQ];
  __shared__ unsigned ky[TSEQ];
  __shared__ float    qv[HD];
  __shared__ float    nzv[4];
  __shared__ int      nzi[4];
  __shared__ int      s_nnz;
  __shared__ int      hist[256];
  __shared__ float    redf[4];
  __shared__ int      redi[4];
  __shared__ int      s_rem;
  __shared__ unsigned s_pref;
  __shared__ float    s_m;
  __shared__ int      sel_k[64];
  __shared__ float    sel_p[64];
  __shared__ float    oacc[4][64];
  __shared__ float    s_z;

  if (tid < 64) qv[tid] = Qy[((size_t)(b * TSEQ + q)) * 1024 + h * HD + tid];
  if (tid == 0) { s_rem = 64; s_pref = 0u; s_nnz = 0; }
  __syncthreads();

  // extract <=4 nonzeros of q (index order, deterministic)
  if (wid == 0) {
    float v = qv[lane];
    unsigned long long mk = __ballot(v != 0.0f);
    if (v != 0.0f) {
      int rk = (int)__popcll(mk & ((1ull << lane) - 1ull));
      if (rk < 4) { nzi[rk] = lane; nzv[rk] = v; }
    }
    if (lane == 0) { int c = (int)__popcll(mk); s_nnz = c < 4 ? c : 4; }
  }
  __syncthreads();
  const int nnz = s_nnz;

  // scores via q's nonzeros against KT rows (coalesced)
  const float* ktb = KT + (size_t)bh * HD * TSEQ;
  float mloc = -INFINITY;
  for (int k0 = 0; k0 < TSEQ; k0 += 256) {
    const int k = k0 + tid;
    float s; unsigned u;
    if (k <= q) {
      s = 0.0f;
      for (int j = 0; j < nnz; ++j)
        s += nzv[j] * ktb[(size_t)nzi[j] * TSEQ + k];
      s *= 0.125f;                 // 1/sqrt(64)
      u = mono_key(s);
    } else { s = -INFINITY; u = 0u; }
    sc[k] = s; ky[k] = u;
    mloc = fmaxf(mloc, s);
  }
#pragma unroll
  for (int off = 32; off > 0; off >>= 1) mloc = fmaxf(mloc, __shfl_xor(mloc, off));
  if (lane == 0) redf[wid] = mloc;
  __syncthreads();
  if (tid == 0) s_m = fmaxf(fmaxf(redf[0], redf[1]), fmaxf(redf[2], redf[3]));
  __syncthreads();

  const int nvalid = q + 1;
  unsigned t_u; int need_eq;
  if (nvalid > 64) {
    // exact radix select: 64th largest key (invalid sentinel 0 excluded)
    for (int pass = 0; pass < 4; ++pass) {
      const int shift = 24 - 8 * pass;
      hist[tid] = 0;
      __syncthreads();
      const unsigned pref = s_pref;
      for (int i = 0; i < 4; ++i) {
        const unsigned kk = ky[i * 256 + tid];
        bool part = (kk != 0u);
        if (pass > 0) part = part && ((kk >> (shift + 8)) == (pref >> (shift + 8)));
        const unsigned digit = (kk >> shift) & 255u;
        if (part) {
          unsigned long long mm = __ballot(true);
#pragma unroll
          for (int bit = 0; bit < 8; ++bit) {
            unsigned long long bb = __ballot((int)((digit >> bit) & 1u));
            mm &= ((digit >> bit) & 1u) ? bb : ~bb;
          }
          if (lane == __ffsll((unsigned long long)mm) - 1)
            atomicAdd(&hist[digit], (int)__popcll(mm));
        }
      }
      __syncthreads();
      if (wid == 0) {
        const int d0 = lane << 2;
        const int c0 = hist[d0], c1 = hist[d0 + 1], c2 = hist[d0 + 2], c3 = hist[d0 + 3];
        const int sum = c0 + c1 + c2 + c3;
        int S = sum;
#pragma unroll
        for (int off = 1; off < 64; off <<= 1) {
          int t = __shfl_down(S, off);
          if (lane + off < 64) S += t;
        }
        const int above = S - sum;       // count of digits in higher lanes
        const int cg3 = above;
        const int cg2 = above + c3;
        const int cg1 = above + c3 + c2;
        const int cg0 = above + c3 + c2 + c1;
        const int rem = s_rem;
        if (cg0 < rem && rem <= cg0 + c0) { s_pref = pref | ((unsigned)(d0 + 0) << shift); s_rem = rem - cg0; }
        if (cg1 < rem && rem <= cg1 + c1) { s_pref = pref | ((unsigned)(d0 + 1) << shift); s_rem = rem - cg1; }
        if (cg2 < rem && rem <= cg2 + c2) { s_pref = pref | ((unsigned)(d0 + 2) << shift); s_rem = rem - cg2; }
        if (cg3 < rem && rem <= cg3 + c3) { s_pref = pref | ((unsigned)(d0 + 3) << shift); s_rem = rem - cg3; }
      }
      __syncthreads();
    }
    t_u = s_pref;
    need_eq = s_rem;
  } else {
    t_u = 0u;       // select all valid (key>0); -inf rest get weight 0, matches ref
    need_eq = 0;
  }

  // selection with index-ordered tie-break + compaction (blocked: tid*4..+3)
  unsigned kk4[4]; int eqf[4];
  int tsum = 0;
#pragma unroll
  for (int i = 0; i < 4; ++i) {
    kk4[i] = ky[(tid << 2) + i];
    eqf[i] = (t_u != 0u && kk4[i] == t_u) ? 1 : 0;
    tsum += eqf[i];
  }
  int cum = tsum;
#pragma unroll
  for (int off = 1; off < 64; off <<= 1) {
    int t = __shfl_up(cum, off);
    if (lane >= off) cum += t;
  }
  if (lane == 63) redi[wid] = cum;
  __syncthreads();
  int woff = 0;
  for (int w = 0; w < wid; ++w) woff += redi[w];
  const int ex_eq = woff + cum - tsum;
  __syncthreads();

  int self_[4];
  int run = ex_eq, tsel = 0;
#pragma unroll
  for (int i = 0; i < 4; ++i) {
    const bool sb = (kk4[i] > t_u) || (eqf[i] && run < need_eq);
    run += eqf[i];
    self_[i] = sb ? 1 : 0;
    tsel += self_[i];
  }
  int cum2 = tsel;
#pragma unroll
  for (int off = 1; off < 64; off <<= 1) {
    int t = __shfl_up(cum2, off);
    if (lane >= off) cum2 += t;
  }
  if (lane == 63) redi[wid] = cum2;
  __syncthreads();
  int woff2 = 0;
  for (int w = 0; w < wid; ++w) woff2 += redi[w];
  const int nsel = redi[0] + redi[1] + redi[2] + redi[3];
  int pos = woff2 + cum2 - tsel;

  const float m = s_m;
  float zpart = 0.0f;
#pragma unroll
  for (int i = 0; i < 4; ++i) {
    if (self_[i]) {
      const int k = (tid << 2) + i;
      const float p = __expf(sc[k] - m);
      sel_k[pos] = k; sel_p[pos] = p;
      ++pos;
      zpart += p;
    }
  }
#pragma unroll
  for (int off = 32; off > 0; off >>= 1) zpart += __shfl_xor(zpart, off);
  if (lane == 0) redf[wid] = zpart;
  __syncthreads();
  if (tid == 0) s_z = redf[0] + redf[1] + redf[2] + redf[3];
  __syncthreads();

  // epilogue: out[d] = sum_sel p * V[k][d] / Z ; 4 wave-groups over entries
  float acc = 0.0f;
  const float* vb = Vy + ((size_t)b * TSEQ) * 1024 + h * HD + lane;
  for (int s2 = wid; s2 < nsel; s2 += 4)
    acc += sel_p[s2] * vb[(size_t)sel_k[s2] * 1024];
  oacc[wid][lane] = acc;
  __syncthreads();
  if (wid == 0) {
    const float r = (oacc[0][lane] + oacc[1][lane]) + (oacc[2][lane] + oacc[3][lane]);
    Oy[((size_t)(b * TSEQ + q)) * 1024 + h * HD + lane] = r / s_z;
  }
}

// ---------------- launch -----------------------------------------------------
extern "C" void kernel_launch(void* const* d_in, const int* in_sizes, int n_in,
                              void* d_out, int out_size, void* d_ws, size_t ws_size,
                              hipStream_t stream) {
  (void)in_sizes; (void)n_in; (void)out_size; (void)ws_size;
  const float* x  = (const float*)d_in[0];
  const float* wq = (const float*)d_in[1];
  const float* wk = (const float*)d_in[2];
  const float* wv = (const float*)d_in[3];
  const float* wo = (const float*)d_in[4];
  float* out = (float*)d_out;

  float* ws = (float*)d_ws;
  const size_t SZ = (size_t)4096 * 1024;   // 4M floats per buffer
  float* qy = ws;
  float* kyb = ws + SZ;
  float* vy = ws + 2 * SZ;
  float* kt = ws + 3 * SZ;
  float* oy = kyb;                         // kyb dead after transpose

  const dim3 gg(1024 / BN, 4096 / BM);
  gemm_nt<<<gg, 256, 0, stream>>>(x, wq, qy, 4096, 1024, 1024);
  gemm_nt<<<gg, 256, 0, stream>>>(x, wk, kyb, 4096, 1024, 1024);
  gemm_nt<<<gg, 256, 0, stream>>>(x, wv, vy, 4096, 1024, 1024);

  sparsify_top4<<<65536 / 4, 256, 0, stream>>>(qy, 65536);
  sparsify_top4<<<65536 / 4, 256, 0, stream>>>(kyb, 65536);
  sparsify_top4<<<65536 / 4, 256, 0, stream>>>(vy, 65536);

  transpose_k<<<dim3(TSEQ / 64, 64), 256, 0, stream>>>(kyb, kt);

  attn_sparse<<<dim3(TSEQ, 64), 256, 0, stream>>>(qy, kt, vy, oy);

  gemm_nt<<<gg, 256, 0, stream>>>(oy, wo, out, 4096, 1024, 1024);
}

// Round 2
// 1112.859 us; speedup vs baseline: 1.0465x; 1.0465x over previous
//
#include <hip/hip_runtime.h>
#include <math.h>

#define TSEQ 1024
#define NH 16
#define HD 64

// ---------------- fp32 GEMM: C[M,N] = A[M,K] * B[N,K]^T (both row-major) ----
#define BM 128
#define BN 128
#define BK 16

__global__ __launch_bounds__(256) void gemm_nt(
    const float* __restrict__ A, const float* __restrict__ B,
    float* __restrict__ C, int M, int N, int K)
{
  __shared__ float As[BK][BM + 4];
  __shared__ float Bs[BK][BN + 4];
  const int tid = threadIdx.x;
  const int bm = blockIdx.y * BM;
  const int bn = blockIdx.x * BN;
  const int tm = (tid >> 4) << 3;
  const int tn = (tid & 15) << 3;

  float acc[8][8];
#pragma unroll
  for (int i = 0; i < 8; ++i)
#pragma unroll
    for (int j = 0; j < 8; ++j) acc[i][j] = 0.0f;

  const int lr = tid >> 2;          // 0..63
  const int lc = (tid & 3) << 2;    // 0,4,8,12
  const float* Ap = A + (size_t)(bm + lr) * K + lc;
  const float* Bp = B + (size_t)(bn + lr) * K + lc;

  for (int k0 = 0; k0 < K; k0 += BK) {
    float4 a0 = *(const float4*)(Ap + k0);
    float4 a1 = *(const float4*)(Ap + (size_t)64 * K + k0);
    float4 b0 = *(const float4*)(Bp + k0);
    float4 b1 = *(const float4*)(Bp + (size_t)64 * K + k0);
    As[lc + 0][lr] = a0.x; As[lc + 1][lr] = a0.y; As[lc + 2][lr] = a0.z; As[lc + 3][lr] = a0.w;
    As[lc + 0][lr + 64] = a1.x; As[lc + 1][lr + 64] = a1.y; As[lc + 2][lr + 64] = a1.z; As[lc + 3][lr + 64] = a1.w;
    Bs[lc + 0][lr] = b0.x; Bs[lc + 1][lr] = b0.y; Bs[lc + 2][lr] = b0.z; Bs[lc + 3][lr] = b0.w;
    Bs[lc + 0][lr + 64] = b1.x; Bs[lc + 1][lr + 64] = b1.y; Bs[lc + 2][lr + 64] = b1.z; Bs[lc + 3][lr + 64] = b1.w;
    __syncthreads();
#pragma unroll
    for (int kk = 0; kk < BK; ++kk) {
      float4 av0 = *(const float4*)&As[kk][tm];
      float4 av1 = *(const float4*)&As[kk][tm + 4];
      float4 bv0 = *(const float4*)&Bs[kk][tn];
      float4 bv1 = *(const float4*)&Bs[kk][tn + 4];
      float a[8] = {av0.x, av0.y, av0.z, av0.w, av1.x, av1.y, av1.z, av1.w};
      float bb[8] = {bv0.x, bv0.y, bv0.z, bv0.w, bv1.x, bv1.y, bv1.z, bv1.w};
#pragma unroll
      for (int i = 0; i < 8; ++i)
#pragma unroll
        for (int j = 0; j < 8; ++j) acc[i][j] = fmaf(a[i], bb[j], acc[i][j]);
    }
    __syncthreads();
  }
#pragma unroll
  for (int i = 0; i < 8; ++i) {
    float* Cp = C + (size_t)(bm + tm + i) * N + bn + tn;
    *(float4*)Cp = make_float4(acc[i][0], acc[i][1], acc[i][2], acc[i][3]);
    *(float4*)(Cp + 4) = make_float4(acc[i][4], acc[i][5], acc[i][6], acc[i][7]);
  }
}

// ---------------- top-4 |v| sparsify, one wave per 64-vector, in place ------
__global__ __launch_bounds__(256) void sparsify_top4(float* __restrict__ y, int nvec)
{
  const int w = blockIdx.x * 4 + (threadIdx.x >> 6);
  const int lane = threadIdx.x & 63;
  if (w >= nvec) return;
  float* p = y + (size_t)w * 64;
  const float v = p[lane];
  float ak = fabsf(v);      // working key; -1 once consumed
  bool sel = false;
#pragma unroll
  for (int it = 0; it < 4; ++it) {
    float bv = ak; int bl = lane;
#pragma unroll
    for (int off = 32; off > 0; off >>= 1) {
      float ov = __shfl_xor(bv, off);
      int   ol = __shfl_xor(bl, off);
      if (ov > bv || (ov == bv && ol < bl)) { bv = ov; bl = ol; }
    }
    if (lane == bl) { sel = true; ak = -1.0f; }
  }
  p[lane] = sel ? v : 0.0f;
}

// ---------------- K relayout: [b,t,h,j] -> KT [bh, j, t] --------------------
__global__ __launch_bounds__(256) void transpose_k(
    const float* __restrict__ Ky, float* __restrict__ KT)
{
  __shared__ float tile[64][65];
  const int bh = blockIdx.y;
  const int b = bh >> 4, h = bh & 15;
  const int t0 = blockIdx.x * 64;
  const int tid = threadIdx.x;
  {
    const int j = tid & 63, r = tid >> 6;
#pragma unroll
    for (int i = 0; i < 16; ++i) {
      const int tl = r * 16 + i;
      tile[tl][j] = Ky[(size_t)(b * TSEQ + t0 + tl) * 1024 + h * HD + j];
    }
  }
  __syncthreads();
  {
    const int tl = tid & 63, jr = tid >> 6;
#pragma unroll
    for (int i = 0; i < 16; ++i) {
      const int jl = jr * 16 + i;
      KT[((size_t)(bh * HD + jl)) * TSEQ + t0 + tl] = tile[tl][jl];
    }
  }
}

// ---------------- attention: one block per (q, bh) --------------------------
__device__ __forceinline__ unsigned mono_key(float f) {
  unsigned b = __float_as_uint(f);
  return (b & 0x80000000u) ? ~b : (b | 0x80000000u);
}

__global__ __launch_bounds__(256) void attn_sparse(
    const float* __restrict__ Qy, const float* __restrict__ KT,
    const float* __restrict__ Vy, float* __restrict__ Oy)
{
  const int q  = blockIdx.x;
  const int bh = blockIdx.y;
  const int b  = bh >> 4;
  const int h  = bh & 15;
  const int tid  = threadIdx.x;
  const int lane = tid & 63;
  const int wid  = tid >> 6;

  __shared__ float    sc[TSEQ];
  __shared__ unsigned ky[TSEQ];
  __shared__ float    qv[HD];
  __shared__ float    nzv[4];
  __shared__ int      nzi[4];
  __shared__ int      s_nnz;
  __shared__ int      hist[256];
  __shared__ float    redf[4];
  __shared__ int      redi[4];
  __shared__ int      redi2[4];
  __shared__ int      s_rem;
  __shared__ unsigned s_pref;
  __shared__ float    s_m;
  __shared__ int      s_npos;
  __shared__ int      s_npz;
  __shared__ int      sel_k[64];
  __shared__ float    sel_p[64];
  __shared__ float    oacc[4][64];
  __shared__ float    s_z;

  if (tid < 64) qv[tid] = Qy[((size_t)(b * TSEQ + q)) * 1024 + h * HD + tid];
  if (tid == 0) { s_rem = 64; s_pref = 0u; s_nnz = 0; }
  __syncthreads();

  // extract <=4 nonzeros of q (index order, deterministic)
  if (wid == 0) {
    float v = qv[lane];
    unsigned long long mk = __ballot(v != 0.0f);
    if (v != 0.0f) {
      int rk = (int)__popcll(mk & ((1ull << lane) - 1ull));
      if (rk < 4) { nzi[rk] = lane; nzv[rk] = v; }
    }
    if (lane == 0) { int c = (int)__popcll(mk); s_nnz = c < 4 ? c : 4; }
  }
  __syncthreads();
  const int nnz = s_nnz;
  const int nvalid = q + 1;

  // scores via q's nonzeros against KT rows (coalesced); only k < nvalid.
  // Track max, count of strictly-positive scores, count of +0.0 scores.
  const float* ktb = KT + (size_t)bh * HD * TSEQ;
  float mloc = -INFINITY;
  int cpos = 0, cpz = 0;
  for (int k0 = 0; k0 < nvalid; k0 += 256) {
    const int k = k0 + tid;
    if (k < nvalid) {
      float s = 0.0f;
      for (int j = 0; j < nnz; ++j)
        s += nzv[j] * ktb[(size_t)nzi[j] * TSEQ + k];
      s *= 0.125f;                 // 1/sqrt(64)
      const unsigned u = mono_key(s);
      sc[k] = s; ky[k] = u;
      mloc = fmaxf(mloc, s);
      cpos += (u > 0x80000000u) ? 1 : 0;   // strictly positive (total order)
      cpz  += (u == 0x80000000u) ? 1 : 0;  // exactly +0.0
    }
  }
#pragma unroll
  for (int off = 32; off > 0; off >>= 1) {
    mloc = fmaxf(mloc, __shfl_xor(mloc, off));
    cpos += __shfl_xor(cpos, off);
    cpz  += __shfl_xor(cpz, off);
  }
  if (lane == 0) { redf[wid] = mloc; redi[wid] = cpos; redi2[wid] = cpz; }
  __syncthreads();
  if (tid == 0) {
    s_m = fmaxf(fmaxf(redf[0], redf[1]), fmaxf(redf[2], redf[3]));
    s_npos = redi[0] + redi[1] + redi[2] + redi[3];
    s_npz  = redi2[0] + redi2[1] + redi2[2] + redi2[3];
  }
  __syncthreads();
  const int npos = s_npos;
  const int npz  = s_npz;

  unsigned t_u; int need_eq;
  if (nvalid <= 64) {
    t_u = 0u;                      // select all valid (every real key > 0)
    need_eq = 0;
  } else if (npos <= 64 && npos + npz >= 64) {
    // FAST PATH: 64th-largest key is exactly key(+0.0) (or boundary is the
    // smallest positive when npos==64). Identical total order + index-ordered
    // tie-break as the radix would produce.
    t_u = 0x80000000u;             // mono_key(+0.0f)
    need_eq = 64 - npos;
  } else {
    // exact radix select: 64th largest key among valid k
    __syncthreads();
    for (int pass = 0; pass < 4; ++pass) {
      const int shift = 24 - 8 * pass;
      hist[tid] = 0;
      __syncthreads();
      const unsigned pref = s_pref;
      for (int i = 0; i < 4; ++i) {
        const int k = i * 256 + tid;
        if (k - tid >= nvalid) break;      // whole-chunk skip (uniform)
        bool part = (k < nvalid);
        const unsigned kk = part ? ky[k] : 0u;
        if (pass > 0) part = part && ((kk >> (shift + 8)) == (pref >> (shift + 8)));
        const unsigned digit = (kk >> shift) & 255u;
        if (part) {
          unsigned long long mm = __ballot(true);
#pragma unroll
          for (int bit = 0; bit < 8; ++bit) {
            unsigned long long bb = __ballot((int)((digit >> bit) & 1u));
            mm &= ((digit >> bit) & 1u) ? bb : ~bb;
          }
          if (lane == __ffsll((unsigned long long)mm) - 1)
            atomicAdd(&hist[digit], (int)__popcll(mm));
        }
      }
      __syncthreads();
      if (wid == 0) {
        const int d0 = lane << 2;
        const int c0 = hist[d0], c1 = hist[d0 + 1], c2 = hist[d0 + 2], c3 = hist[d0 + 3];
        const int sum = c0 + c1 + c2 + c3;
        int S = sum;
#pragma unroll
        for (int off = 1; off < 64; off <<= 1) {
          int t = __shfl_down(S, off);
          if (lane + off < 64) S += t;
        }
        const int above = S - sum;       // count of digits in higher lanes
        const int cg3 = above;
        const int cg2 = above + c3;
        const int cg1 = above + c3 + c2;
        const int cg0 = above + c3 + c2 + c1;
        const int rem = s_rem;
        if (cg0 < rem && rem <= cg0 + c0) { s_pref = pref | ((unsigned)(d0 + 0) << shift); s_rem = rem - cg0; }
        if (cg1 < rem && rem <= cg1 + c1) { s_pref = pref | ((unsigned)(d0 + 1) << shift); s_rem = rem - cg1; }
        if (cg2 < rem && rem <= cg2 + c2) { s_pref = pref | ((unsigned)(d0 + 2) << shift); s_rem = rem - cg2; }
        if (cg3 < rem && rem <= cg3 + c3) { s_pref = pref | ((unsigned)(d0 + 3) << shift); s_rem = rem - cg3; }
      }
      __syncthreads();
    }
    t_u = s_pref;
    need_eq = s_rem;
  }

  // selection with index-ordered tie-break + compaction (blocked: tid*4..+3)
  unsigned kk4[4]; int eqf[4];
  int tsum = 0;
#pragma unroll
  for (int i = 0; i < 4; ++i) {
    const int k = (tid << 2) + i;
    kk4[i] = (k < nvalid) ? ky[k] : 0u;
    eqf[i] = (t_u != 0u && kk4[i] == t_u) ? 1 : 0;
    tsum += eqf[i];
  }
  int cum = tsum;
#pragma unroll
  for (int off = 1; off < 64; off <<= 1) {
    int t = __shfl_up(cum, off);
    if (lane >= off) cum += t;
  }
  if (lane == 63) redi[wid] = cum;
  __syncthreads();
  int woff = 0;
  for (int w = 0; w < wid; ++w) woff += redi[w];
  const int ex_eq = woff + cum - tsum;
  __syncthreads();

  int self_[4];
  int run = ex_eq, tsel = 0;
#pragma unroll
  for (int i = 0; i < 4; ++i) {
    const bool sb = (kk4[i] > t_u) || (eqf[i] && run < need_eq);
    run += eqf[i];
    self_[i] = sb ? 1 : 0;
    tsel += self_[i];
  }
  int cum2 = tsel;
#pragma unroll
  for (int off = 1; off < 64; off <<= 1) {
    int t = __shfl_up(cum2, off);
    if (lane >= off) cum2 += t;
  }
  if (lane == 63) redi[wid] = cum2;
  __syncthreads();
  int woff2 = 0;
  for (int w = 0; w < wid; ++w) woff2 += redi[w];
  const int nsel = redi[0] + redi[1] + redi[2] + redi[3];
  int pos = woff2 + cum2 - tsel;

  const float m = s_m;
  float zpart = 0.0f;
#pragma unroll
  for (int i = 0; i < 4; ++i) {
    if (self_[i]) {
      const int k = (tid << 2) + i;
      const float p = __expf(sc[k] - m);
      sel_k[pos] = k; sel_p[pos] = p;
      ++pos;
      zpart += p;
    }
  }
#pragma unroll
  for (int off = 32; off > 0; off >>= 1) zpart += __shfl_xor(zpart, off);
  if (lane == 0) redf[wid] = zpart;
  __syncthreads();
  if (tid == 0) s_z = redf[0] + redf[1] + redf[2] + redf[3];
  __syncthreads();

  // epilogue: out[d] = sum_sel p * V[k][d] / Z ; 4 wave-groups over entries
  float acc = 0.0f;
  const float* vb = Vy + ((size_t)b * TSEQ) * 1024 + h * HD + lane;
  for (int s2 = wid; s2 < nsel; s2 += 4)
    acc += sel_p[s2] * vb[(size_t)sel_k[s2] * 1024];
  oacc[wid][lane] = acc;
  __syncthreads();
  if (wid == 0) {
    const float r = (oacc[0][lane] + oacc[1][lane]) + (oacc[2][lane] + oacc[3][lane]);
    Oy[((size_t)(b * TSEQ + q)) * 1024 + h * HD + lane] = r / s_z;
  }
}

// ---------------- launch -----------------------------------------------------
extern "C" void kernel_launch(void* const* d_in, const int* in_sizes, int n_in,
                              void* d_out, int out_size, void* d_ws, size_t ws_size,
                              hipStream_t stream) {
  (void)in_sizes; (void)n_in; (void)out_size; (void)ws_size;
  const float* x  = (const float*)d_in[0];
  const float* wq = (const float*)d_in[1];
  const float* wk = (const float*)d_in[2];
  const float* wv = (const float*)d_in[3];
  const float* wo = (const float*)d_in[4];
  float* out = (float*)d_out;

  float* ws = (float*)d_ws;
  const size_t SZ = (size_t)4096 * 1024;   // 4M floats per buffer
  float* qy = ws;
  float* kyb = ws + SZ;
  float* vy = ws + 2 * SZ;
  float* kt = ws + 3 * SZ;
  float* oy = kyb;                         // kyb dead after transpose

  const dim3 gg(1024 / BN, 4096 / BM);
  gemm_nt<<<gg, 256, 0, stream>>>(x, wq, qy, 4096, 1024, 1024);
  gemm_nt<<<gg, 256, 0, stream>>>(x, wk, kyb, 4096, 1024, 1024);
  gemm_nt<<<gg, 256, 0, stream>>>(x, wv, vy, 4096, 1024, 1024);

  sparsify_top4<<<65536 / 4, 256, 0, stream>>>(qy, 65536);
  sparsify_top4<<<65536 / 4, 256, 0, stream>>>(kyb, 65536);
  sparsify_top4<<<65536 / 4, 256, 0, stream>>>(vy, 65536);

  transpose_k<<<dim3(TSEQ / 64, 64), 256, 0, stream>>>(kyb, kt);

  attn_sparse<<<dim3(TSEQ, 64), 256, 0, stream>>>(qy, kt, vy, oy);

  gemm_nt<<<gg, 256, 0, stream>>>(oy, wo, out, 4096, 1024, 1024);
}